// Round 6
// baseline (1272.562 us; speedup 1.0000x reference)
//
#include <hip/hip_runtime.h>

#define N_NODES 500000
#define N_EDGES 2000000
#define F_IN 117
#define H 128
#define NLAYERS 3

#define SCAN_E 2048
#define NB_SCAN ((N_NODES + SCAN_E - 1) / SCAN_E)   // 245

typedef __attribute__((ext_vector_type(8))) short short8v;   // 8 bf16 (4 VGPR)
typedef __attribute__((ext_vector_type(4))) float f32x4;

__device__ __forceinline__ unsigned short f2bf(float x) {    // RNE fp32->bf16
    unsigned u = __builtin_bit_cast(unsigned, x);
    u += 0x7FFFu + ((u >> 16) & 1u);
    return (unsigned short)(u >> 16);
}
__device__ __forceinline__ float bf2f(unsigned short s) {
    unsigned u = ((unsigned)s) << 16;
    return __builtin_bit_cast(float, u);
}
// tanh(x) = 1 - 2/(exp(2x)+1): 1 exp2 + 1 rcp, NaN-free at both extremes.
__device__ __forceinline__ float fast_tanh(float x) {
    float e = __builtin_amdgcn_exp2f(x * 2.885390081777927f);   // exp(2x)
    return 1.0f - 2.0f * __builtin_amdgcn_rcpf(e + 1.0f);
}

// ---------------- W prep: fp32 W[K][128] -> bf16 MFMA B-fragment order ----------------
__global__ void prep_w_kernel(const float* __restrict__ Wself,
                              const float* __restrict__ Wneigh,
                              const float* __restrict__ Win,
                              short* __restrict__ Wfrag,     // [3][64][64][8]
                              short* __restrict__ WfragIn) { // [32][64][8]
    const int tid = blockIdx.x * 256 + threadIdx.x;
    const int total_cmb = NLAYERS * 64 * 64;                 // 12288 frags*lanes
    if (tid < total_cmb) {
        const int lane = tid & 63;
        const int fi   = (tid >> 6) & 63;
        const int l    = tid >> 12;
        const int ks = fi & 7, ct = (fi >> 3) & 3, wc = fi >> 5;
        const int c = wc * 64 + ct * 16 + (lane & 15);
        const int kbase = ks * 32 + (lane >> 4) * 8;
        short8v out;
        #pragma unroll
        for (int j = 0; j < 8; ++j) {
            int k = kbase + j;
            float v = (k < 128) ? Wself [(size_t)l * H * H + k * H + c]
                                : Wneigh[(size_t)l * H * H + (k - 128) * H + c];
            out[j] = (short)f2bf(v);
        }
        *(short8v*)(Wfrag + (size_t)tid * 8) = out;
    } else if (tid < total_cmb + 32 * 64) {
        const int t2 = tid - total_cmb;
        const int lane = t2 & 63;
        const int fi   = t2 >> 6;        // 0..31
        const int ks = fi & 3, ct = (fi >> 2) & 3, wc = fi >> 4;
        const int c = wc * 64 + ct * 16 + (lane & 15);
        const int kbase = ks * 32 + (lane >> 4) * 8;
        short8v out;
        #pragma unroll
        for (int j = 0; j < 8; ++j) {
            int k = kbase + j;
            out[j] = (k < F_IN) ? (short)f2bf(Win[(size_t)k * H + c]) : (short)0;
        }
        *(short8v*)(WfragIn + (size_t)t2 * 8) = out;
    }
}

// ---------------- proj: h = bf16(tanh(x @ W_in + b_in)), fp32 x read direct -----------
__global__ __launch_bounds__(512, 2) void proj_mfma(const short* __restrict__ WfragIn,
                                                    const float* __restrict__ bias,
                                                    const float* __restrict__ x,
                                                    unsigned short* __restrict__ hb) {
    const int wave = threadIdx.x >> 6;
    const int lane = threadIdx.x & 63;
    const int wc   = wave & 1;

    short8v Bf[4][4];
    #pragma unroll
    for (int ct = 0; ct < 4; ++ct)
        #pragma unroll
        for (int ks = 0; ks < 4; ++ks)
            Bf[ct][ks] = ((const short8v*)WfragIn)[(size_t)(((wc * 4 + ct) * 4 + ks) * 64 + lane)];

    float bs[4];
    #pragma unroll
    for (int ct = 0; ct < 4; ++ct) bs[ct] = bias[wc * 64 + ct * 16 + (lane & 15)];

    const int cbase = (lane >> 4) * 8;
    const int ntasks = (N_NODES / 16) * 2;   // 62500
    for (int task = blockIdx.x * 8 + wave; task < ntasks; task += gridDim.x * 8) {
        const int r0  = (task >> 1) * 16;
        const int row = r0 + (lane & 15);
        const float* xr = x + (size_t)row * F_IN;

        short8v Af[4];
        #pragma unroll
        for (int ks = 0; ks < 4; ++ks) {
            const int k0 = ks * 32 + cbase;
            short8v a;
            if (row == N_NODES - 1 && k0 + 7 >= F_IN) {   // rare: avoid OOB past x[]
                #pragma unroll
                for (int j = 0; j < 8; ++j) {
                    int k = k0 + j;
                    a[j] = (k < F_IN) ? (short)f2bf(xr[k]) : (short)0;
                }
            } else {
                #pragma unroll
                for (int j = 0; j < 8; ++j) a[j] = (short)f2bf(xr[k0 + j]);
            }
            Af[ks] = a;
        }

        f32x4 acc[4];
        #pragma unroll
        for (int ct = 0; ct < 4; ++ct) acc[ct] = (f32x4){0.f, 0.f, 0.f, 0.f};
        #pragma unroll
        for (int ks = 0; ks < 4; ++ks)
            #pragma unroll
            for (int ct = 0; ct < 4; ++ct)
                acc[ct] = __builtin_amdgcn_mfma_f32_16x16x32_bf16(Af[ks], Bf[ct][ks], acc[ct], 0, 0, 0);

        #pragma unroll
        for (int ct = 0; ct < 4; ++ct) {
            const int col = wc * 64 + ct * 16 + (lane & 15);
            #pragma unroll
            for (int q = 0; q < 4; ++q) {
                float v = fast_tanh(acc[ct][q] + bs[ct]);
                hb[(size_t)(r0 + (lane >> 4) * 4 + q) * H + col] = f2bf(v);
            }
        }
    }
}

// ---------------- CSR build ----------------
__global__ void zero_int_kernel(int* __restrict__ p, int n) {
    int i = blockIdx.x * blockDim.x + threadIdx.x;
    if (i < n) p[i] = 0;
}

__global__ void hist_kernel(const int* __restrict__ dst, int* __restrict__ cnt) {
    int e = blockIdx.x * blockDim.x + threadIdx.x;
    if (e < N_EDGES) atomicAdd(&cnt[dst[e]], 1);
}

__global__ __launch_bounds__(256) void scan_reduce_kernel(const int* __restrict__ cnt,
                                                          int* __restrict__ bsums) {
    __shared__ int s[256];
    const int base = blockIdx.x * SCAN_E;
    int sum = 0;
    for (int i = threadIdx.x; i < SCAN_E; i += 256) {
        int idx = base + i;
        sum += (idx < N_NODES) ? cnt[idx] : 0;
    }
    s[threadIdx.x] = sum;
    __syncthreads();
    for (int off = 128; off > 0; off >>= 1) {
        if (threadIdx.x < off) s[threadIdx.x] += s[threadIdx.x + off];
        __syncthreads();
    }
    if (threadIdx.x == 0) bsums[blockIdx.x] = s[0];
}

__global__ void scan_bsums_kernel(int* __restrict__ bsums) {   // 1 block, 256 threads
    __shared__ int s[256];
    const int tid = threadIdx.x;
    int v = (tid < NB_SCAN) ? bsums[tid] : 0;
    s[tid] = v;
    __syncthreads();
    for (int off = 1; off < 256; off <<= 1) {
        int add = (tid >= off) ? s[tid - off] : 0;
        __syncthreads();
        s[tid] += add;
        __syncthreads();
    }
    if (tid < NB_SCAN) bsums[tid] = s[tid] - v;   // exclusive
}

__global__ __launch_bounds__(256) void scan_final_kernel(const int* __restrict__ cnt,
                                                         const int* __restrict__ bsums,
                                                         int* __restrict__ start,
                                                         int* __restrict__ cursor,
                                                         float* __restrict__ inv) {
    __shared__ int tsum[256];
    const int tid = threadIdx.x;
    const int base = blockIdx.x * SCAN_E + tid * 8;
    int c[8];
    int s = 0;
    #pragma unroll
    for (int k = 0; k < 8; ++k) {
        int idx = base + k;
        c[k] = (idx < N_NODES) ? cnt[idx] : 0;
        s += c[k];
    }
    tsum[tid] = s;
    __syncthreads();
    for (int off = 1; off < 256; off <<= 1) {
        int add = (tid >= off) ? tsum[tid - off] : 0;
        __syncthreads();
        tsum[tid] += add;
        __syncthreads();
    }
    int off0 = bsums[blockIdx.x] + tsum[tid] - s;
    #pragma unroll
    for (int k = 0; k < 8; ++k) {
        int idx = base + k;
        if (idx < N_NODES) {
            start[idx]  = off0;
            cursor[idx] = off0;
            inv[idx]    = 1.0f / fmaxf((float)c[k], 1.0f);
            off0 += c[k];
        }
    }
}

__global__ void fill_kernel(const int* __restrict__ src, const int* __restrict__ dst,
                            int* __restrict__ cursor, int* __restrict__ srcs) {
    int e = blockIdx.x * blockDim.x + threadIdx.x;
    if (e < N_EDGES) {
        int pos = atomicAdd(&cursor[dst[e]], 1);
        srcs[pos] = src[e];
    }
}

// ---- fused combine: out = relu(h @ Ws + mean_nbr(h) @ Wn + b), gather in-register ----
// Wave-task = 16 rows x 64 cols. Lane owns row r0+(lane&15), col-slice cbase=(lane>>4)*8:
// accumulates its 4x8 ns slice in fp32 over the row's neighbor list, converts to bf16
// A-fragments, runs K=256 MFMA. No ns buffer, no extra dispatch.
__global__ __launch_bounds__(512, 2) void fused_combine(const short* __restrict__ Wfrag,
                                                        const float* __restrict__ bias,
                                                        const int* __restrict__ start,
                                                        const int* __restrict__ cnt,
                                                        const int* __restrict__ srcs,
                                                        const float* __restrict__ inv,
                                                        const unsigned short* __restrict__ hb,
                                                        unsigned short* __restrict__ outb,
                                                        float* __restrict__ outf,
                                                        int last) {
    const int wave = threadIdx.x >> 6;
    const int lane = threadIdx.x & 63;
    const int wc   = wave & 1;

    short8v Bf[4][8];
    #pragma unroll
    for (int ct = 0; ct < 4; ++ct)
        #pragma unroll
        for (int ks = 0; ks < 8; ++ks)
            Bf[ct][ks] = ((const short8v*)Wfrag)[(size_t)(((wc * 4 + ct) * 8 + ks) * 64 + lane)];

    float bs[4];
    #pragma unroll
    for (int ct = 0; ct < 4; ++ct) bs[ct] = bias[wc * 64 + ct * 16 + (lane & 15)];

    const int cbase = (lane >> 4) * 8;
    const int ntasks = (N_NODES / 16) * 2;   // 62500
    for (int task = blockIdx.x * 8 + wave; task < ntasks; task += gridDim.x * 8) {
        const int r0  = (task >> 1) * 16;
        const int row = r0 + (lane & 15);

        // self A-fragments
        const unsigned short* arow = hb + (size_t)row * H + cbase;
        short8v Af[4];
        #pragma unroll
        for (int ks = 0; ks < 4; ++ks) Af[ks] = *(const short8v*)(arow + ks * 32);

        // in-register neighbor mean (this lane's 4x8 col slice)
        float na[4][8];
        #pragma unroll
        for (int ks = 0; ks < 4; ++ks)
            #pragma unroll
            for (int i = 0; i < 8; ++i) na[ks][i] = 0.f;

        const int st = start[row];
        const int c  = cnt[row];
        for (int j = 0; j < c; ++j) {
            const unsigned short* nb = hb + (size_t)srcs[st + j] * H + cbase;
            const short8v v0 = *(const short8v*)(nb + 0);
            const short8v v1 = *(const short8v*)(nb + 32);
            const short8v v2 = *(const short8v*)(nb + 64);
            const short8v v3 = *(const short8v*)(nb + 96);
            #pragma unroll
            for (int i = 0; i < 8; ++i) {
                na[0][i] += bf2f((unsigned short)v0[i]);
                na[1][i] += bf2f((unsigned short)v1[i]);
                na[2][i] += bf2f((unsigned short)v2[i]);
                na[3][i] += bf2f((unsigned short)v3[i]);
            }
        }
        const float iv = inv[row];
        short8v An[4];
        #pragma unroll
        for (int ks = 0; ks < 4; ++ks) {
            short8v a;
            #pragma unroll
            for (int i = 0; i < 8; ++i) a[i] = (short)f2bf(na[ks][i] * iv);
            An[ks] = a;
        }

        f32x4 acc[4];
        #pragma unroll
        for (int ct = 0; ct < 4; ++ct) acc[ct] = (f32x4){0.f, 0.f, 0.f, 0.f};
        #pragma unroll
        for (int ks = 0; ks < 4; ++ks)
            #pragma unroll
            for (int ct = 0; ct < 4; ++ct)
                acc[ct] = __builtin_amdgcn_mfma_f32_16x16x32_bf16(Af[ks], Bf[ct][ks], acc[ct], 0, 0, 0);
        #pragma unroll
        for (int ks = 0; ks < 4; ++ks)
            #pragma unroll
            for (int ct = 0; ct < 4; ++ct)
                acc[ct] = __builtin_amdgcn_mfma_f32_16x16x32_bf16(An[ks], Bf[ct][4 + ks], acc[ct], 0, 0, 0);

        if (!last) {
            #pragma unroll
            for (int ct = 0; ct < 4; ++ct) {
                const int col = wc * 64 + ct * 16 + (lane & 15);
                #pragma unroll
                for (int q = 0; q < 4; ++q) {
                    float v = fmaxf(acc[ct][q] + bs[ct], 0.f);
                    outb[(size_t)(r0 + (lane >> 4) * 4 + q) * H + col] = f2bf(v);
                }
            }
        } else {
            #pragma unroll
            for (int ct = 0; ct < 4; ++ct) {
                const int col = wc * 64 + ct * 16 + (lane & 15);
                #pragma unroll
                for (int q = 0; q < 4; ++q) {
                    float v = fmaxf(acc[ct][q] + bs[ct], 0.f);
                    outf[(size_t)(r0 + (lane >> 4) * 4 + q) * H + col] = v;
                }
            }
        }
    }
}

// ---------------- launch ----------------
extern "C" void kernel_launch(void* const* d_in, const int* in_sizes, int n_in,
                              void* d_out, int out_size, void* d_ws, size_t ws_size,
                              hipStream_t stream) {
    const float* x        = (const float*)d_in[0];
    const int*   edge_src = (const int*)d_in[1];
    const int*   edge_dst = (const int*)d_in[2];
    const float* W_in     = (const float*)d_in[3];
    const float* b_in     = (const float*)d_in[4];
    const float* W_self   = (const float*)d_in[5];
    const float* W_neigh  = (const float*)d_in[6];
    const float* b_layers = (const float*)d_in[7];

    // ws layout (16B-aligned); nsb slot retained but unused after fusion
    unsigned short* h0  = (unsigned short*)d_ws;               // 128 MB
    unsigned short* nsb = h0 + (size_t)N_NODES * H;            // 128 MB (unused)
    int*   cnt    = (int*)(nsb + (size_t)N_NODES * H);         // 2 MB
    int*   start  = cnt + N_NODES;                             // 2 MB
    int*   cursor = start + N_NODES;                           // 2 MB
    float* inv    = (float*)(cursor + N_NODES);                // 2 MB
    int*   srcs   = (int*)(inv + N_NODES);                     // 8 MB
    int*   bsums  = srcs + N_EDGES;                            // 1 KB
    short* Wfrag  = (short*)(bsums + 256);                     // 192 KB  [3][64][64][8]
    short* WfragIn = Wfrag + (size_t)NLAYERS * 64 * 64 * 8;    // 32 KB   [32][64][8]
    // h1 (bf16) lives in d_out's lower 128 MB until the final fp32 write
    unsigned short* h1 = (unsigned short*)d_out;

    prep_w_kernel<<<(NLAYERS * 64 * 64 + 32 * 64 + 255) / 256, 256, 0, stream>>>(
        W_self, W_neigh, W_in, Wfrag, WfragIn);

    // CSR build (edge_dst static)
    zero_int_kernel<<<(N_NODES + 255) / 256, 256, 0, stream>>>(cnt, N_NODES);
    hist_kernel<<<(N_EDGES + 255) / 256, 256, 0, stream>>>(edge_dst, cnt);
    scan_reduce_kernel<<<NB_SCAN, 256, 0, stream>>>(cnt, bsums);
    scan_bsums_kernel<<<1, 256, 0, stream>>>(bsums);
    scan_final_kernel<<<NB_SCAN, 256, 0, stream>>>(cnt, bsums, start, cursor, inv);
    fill_kernel<<<(N_EDGES + 255) / 256, 256, 0, stream>>>(edge_src, edge_dst, cursor, srcs);

    // input projection (MFMA, fused fp32->bf16 convert, fast-tanh epilogue)
    proj_mfma<<<1024, 512, 0, stream>>>(WfragIn, b_in, x, h0);

    // L0: h0 -> h1 ; L1: h1 -> h0 ; L2: h0 -> fp32 d_out   (gather fused in-register)
    fused_combine<<<1024, 512, 0, stream>>>(Wfrag + 0 * 64 * 64 * 8, b_layers + 0 * H,
                                            start, cnt, srcs, inv, h0, h1, nullptr, 0);
    fused_combine<<<1024, 512, 0, stream>>>(Wfrag + 1 * 64 * 64 * 8, b_layers + 1 * H,
                                            start, cnt, srcs, inv, h1, h0, nullptr, 0);
    fused_combine<<<1024, 512, 0, stream>>>(Wfrag + 2 * 64 * 64 * 8, b_layers + 2 * H,
                                            start, cnt, srcs, inv, h0, nullptr, (float*)d_out, 1);
}